// Round 2
// baseline (1887.286 us; speedup 1.0000x reference)
//
#include <hip/hip_runtime.h>

typedef unsigned short u16;
typedef _Float16 f16;
typedef __attribute__((ext_vector_type(8))) _Float16 f16x8;
typedef __attribute__((ext_vector_type(4))) float f32x4;

#define NPTS 65536

__device__ __forceinline__ u16 f2h(float f) {
    f16 h = (f16)f;  // v_cvt_f16_f32, RNE
    return __builtin_bit_cast(u16, h);
}

__device__ __forceinline__ unsigned pack2(float a, float b) {
    return (unsigned)f2h(a) | ((unsigned)f2h(b) << 16);
}

__device__ __forceinline__ void async_copy16(const u16* g, u16* l) {
    __builtin_amdgcn_global_load_lds(
        (const __attribute__((address_space(1))) void*)g,
        (__attribute__((address_space(3))) void*)l, 16, 0, 0);
}

// ---------------- KNN + full x_ assembly (f16, stride 1568) ----------------
// xpad row: [xyz(3) | sel(24) | zeros(5) | latent(1536)]   (one wave per point)
__global__ __launch_bounds__(256) void knn_kernel(const float* __restrict__ cxyz,
                                                  u16* __restrict__ xpad) {
#pragma clang fp contract(off)
    const int lane = threadIdx.x & 63;
    const int wave = threadIdx.x >> 6;
    const size_t p = (size_t)blockIdx.x * 4 + wave;
    const float* row = cxyz + p * 1539;
    u16* orow = xpad + p * 1568;

    float vals[24];
    const float* lp = row + 3 + lane * 24;
#pragma unroll
    for (int i = 0; i < 24; ++i) vals[i] = lp[i];

    float x0 = row[0], y0 = row[1], z0 = row[2];

    unsigned long long cand[8];
#pragma unroll
    for (int t = 0; t < 8; ++t) {
        float dx = x0 - vals[3 * t + 0];
        float dy = y0 - vals[3 * t + 1];
        float dz = z0 - vals[3 * t + 2];
        float d2 = dx * dx + dy * dy;   // contract off: matches np eval order
        d2 = d2 + dz * dz;
        cand[t] = (((unsigned long long)__float_as_uint(d2)) << 32) |
                  (unsigned)(lane * 8 + t);
    }

    for (int r = 0; r < 8; ++r) {
        unsigned long long m = cand[0];
#pragma unroll
        for (int t = 1; t < 8; ++t) m = (cand[t] < m) ? cand[t] : m;
#pragma unroll
        for (int o = 1; o < 64; o <<= 1) {
            unsigned long long o2 = __shfl_xor(m, o, 64);
            m = (o2 < m) ? o2 : m;
        }
#pragma unroll
        for (int t = 0; t < 8; ++t)
            if (cand[t] == m) cand[t] = ~0ULL;
        if (lane == r) {
            unsigned jw = (unsigned)m;
            orow[3 + 3 * r + 0] = f2h(row[3 + 3 * jw + 0]);
            orow[3 + 3 * r + 1] = f2h(row[3 + 3 * jw + 1]);
            orow[3 + 3 * r + 2] = f2h(row[3 + 3 * jw + 2]);
        }
    }

    if (lane < 3) orow[lane] = f2h(row[lane]);
    if (lane >= 27 && lane < 32) orow[lane] = 0;

    // latent: 24 f16 per lane, 16B-aligned vector stores (64 + 48*lane bytes)
    unsigned w[12];
#pragma unroll
    for (int i = 0; i < 12; ++i) w[i] = pack2(vals[2 * i], vals[2 * i + 1]);
    uint4* op = (uint4*)(orow + 32 + lane * 24);
    op[0] = make_uint4(w[0], w[1], w[2], w[3]);
    op[1] = make_uint4(w[4], w[5], w[6], w[7]);
    op[2] = make_uint4(w[8], w[9], w[10], w[11]);
}

// ---------------- weight packing (fp32 -> f16, transpose + K-pad) ----------------
__global__ __launch_bounds__(256) void prep_w1(const float* __restrict__ Wf,
                                               u16* __restrict__ W1p) {
    int idx = blockIdx.x * 256 + threadIdx.x;
    if (idx >= 512 * 1568) return;
    int n = idx / 1568, kp = idx % 1568;
    float v = 0.f;
    if (kp < 27) v = Wf[(size_t)kp * 512 + n];
    else if (kp >= 32) v = Wf[(size_t)(kp - 5) * 512 + n];
    W1p[idx] = f2h(v);
}

__global__ __launch_bounds__(256) void prep_win(const float* __restrict__ Win,
                                                u16* __restrict__ Winp) {
    int idx = blockIdx.x * 256 + threadIdx.x;
    if (idx >= 3 * 512 * 2080) return;
    int b = idx / (512 * 2080);
    int r = idx % (512 * 2080);
    int n = r / 2080, kp = r % 2080;
    float v = 0.f;
    if (kp < 539) v = Win[((size_t)b * 2075 + kp) * 512 + n];
    else if (kp >= 544) v = Win[((size_t)b * 2075 + kp - 5) * 512 + n];
    Winp[idx] = f2h(v);
}

__global__ __launch_bounds__(256) void prep_wh(const float* __restrict__ Wh,
                                               u16* __restrict__ Whp) {
    int idx = blockIdx.x * 256 + threadIdx.x;
    if (idx >= 8 * 512 * 512) return;
    int m = idx / (512 * 512);
    int r = idx % (512 * 512);
    int n = r / 512, k = r % 512;
    Whp[idx] = f2h(Wh[((size_t)m * 512 + k) * 512 + n]);
}

// ---------------- f16 GEMM: C[M x 512] = relu(A @ B^T + bias) ----------------
// Virtual A = [seg0 (kt0 tiles, ld0) | seg1 (kt1 tiles, ld1)], both f16 k-contiguous.
// B packed transposed [512][K] f16, K = (kt0+kt1)*32. bias fp32. C f16.
//
// v3: (a) 3-deep pipeline with raw s_barrier + counted vmcnt(4): tile-t loads
//     drained at step t while tile-(t+1) loads stay in flight ACROSS the
//     barrier (T4). Race ledger: each wave's own vmcnt(4) covers its oldest 4
//     loads (= tile t) before the barrier join -> all tile-t data in LDS before
//     any wave reads; stage(t+2) overwrites tile-(t-1)'s buffer, issued only
//     after the barrier that every wave reaches post-lgkm-drain of its
//     tile-(t-1) ds_reads.
//     (b) XOR swizzle (both-sides): physical quad = logical quad ^ row[2:1].
//     LDS dest stays linear (global_load_lds requirement); the permutation is
//     applied to the per-lane GLOBAL source column and to the ds_read address.
//     Fixes the half-bank 2x ds_read_b128 penalty (1.7e7 conflict cycles).
//     (c) setprio(1) around the MFMA cluster (waves now have role-split).
__global__ __launch_bounds__(256, 3) void gemm_f16(
    const u16* __restrict__ A0, int ld0, int kt0,
    const u16* __restrict__ A1, int ld1, int kt1,
    const u16* __restrict__ B,
    const float* __restrict__ bias,
    u16* __restrict__ C,
    int mb8) {                       // (M/128)/8
    __shared__ u16 As[3][128 * 32];
    __shared__ u16 Bs[3][128 * 32];
    const int tid = threadIdx.x;
    const int lane = tid & 63;
    const int wave = tid >> 6;
    const int ktot = kt0 + kt1;
    const size_t ldB = (size_t)ktot * 32;

    // XCD-aware decode: xcd = bid&7 owns M-blocks [xcd*mb8, (xcd+1)*mb8);
    // within the XCD's stream, n cycles fastest -> same-A blocks co-resident.
    const int bid = blockIdx.x;
    const int idx = bid >> 3;
    const int mb = (bid & 7) * mb8 + (idx >> 2);
    const int nb = idx & 3;
    const size_t mbase = (size_t)mb * 128;
    const int nbase = nb * 128;

    f32x4 acc[4][4];
#pragma unroll
    for (int i = 0; i < 4; ++i)
#pragma unroll
        for (int j = 0; j < 4; ++j) acc[i][j] = (f32x4){0.f, 0.f, 0.f, 0.f};

    const int r4 = lane >> 2;         // 0..15 (row within 16-row half)
    // swizzled source column: logical quad (lane&3) lives at physical quad
    // (lane&3)^(row[2:1]); row[2:1] of this lane's staged row = (lane>>3)&3.
    const int c8s = (((lane & 3) ^ ((lane >> 3) & 3)) * 8);
    const size_t arow0 = mbase + wave * 32 + r4;
    const size_t brow0 = (size_t)nbase + wave * 32 + r4;

    const int m0 = (wave & 1) * 64;
    const int n0 = (wave >> 1) * 64;
    const int rowsel = lane & 15;
    // swizzled read column: physical quad = (lane>>4) ^ rowsel[2:1]
    const int colrd = (((lane >> 4) ^ ((rowsel >> 1) & 3)) * 8);

    auto stage = [&](int t, int b) {
        u16* lA0 = &As[b][(wave * 32 + 0) * 32];
        u16* lA1 = &As[b][(wave * 32 + 16) * 32];
        u16* lB0 = &Bs[b][(wave * 32 + 0) * 32];
        u16* lB1 = &Bs[b][(wave * 32 + 16) * 32];
        if (t < kt0) {
            const size_t off = arow0 * (size_t)ld0 + t * 32 + c8s;
            async_copy16(A0 + off, lA0);
            async_copy16(A0 + off + 16 * (size_t)ld0, lA1);
        } else {
            const size_t off = arow0 * (size_t)ld1 + (t - kt0) * 32 + c8s;
            async_copy16(A1 + off, lA0);
            async_copy16(A1 + off + 16 * (size_t)ld1, lA1);
        }
        const size_t boff = brow0 * ldB + t * 32 + c8s;
        async_copy16(B + boff, lB0);
        async_copy16(B + boff + 16 * ldB, lB1);
    };

    // prologue: fill buffers 0 and 1 (8 loads in flight per wave)
    stage(0, 0);
    if (1 < ktot) stage(1, 1);

    for (int t = 0; t < ktot; ++t) {
        const int cb = t % 3;
        // drain only tile t's loads (oldest 4); tile t+1's stay in flight
        if (t + 1 < ktot) {
            asm volatile("s_waitcnt vmcnt(4)" ::: "memory");
        } else {
            asm volatile("s_waitcnt vmcnt(0)" ::: "memory");
        }
        __builtin_amdgcn_s_barrier();
        __builtin_amdgcn_sched_barrier(0);
        // overwrites tile-(t-1)'s buffer: all waves done reading it (they
        // lgkm-drained those ds_reads before reaching the barrier above)
        if (t + 2 < ktot) stage(t + 2, (t + 2) % 3);

        f16x8 af[4], bfr[4];
#pragma unroll
        for (int i = 0; i < 4; ++i) {
            af[i]  = __builtin_bit_cast(f16x8, *(const uint4*)&As[cb][(m0 + i * 16 + rowsel) * 32 + colrd]);
            bfr[i] = __builtin_bit_cast(f16x8, *(const uint4*)&Bs[cb][(n0 + i * 16 + rowsel) * 32 + colrd]);
        }
        __builtin_amdgcn_s_setprio(1);
#pragma unroll
        for (int i = 0; i < 4; ++i)
#pragma unroll
            for (int j = 0; j < 4; ++j)
                acc[i][j] = __builtin_amdgcn_mfma_f32_16x16x32_f16(
                    af[i], bfr[j], acc[i][j], 0, 0, 0);
        __builtin_amdgcn_s_setprio(0);
    }

    // epilogue: bias + relu -> f16. D layout: col=lane&15, row=(lane>>4)*4+reg
#pragma unroll
    for (int j = 0; j < 4; ++j) {
        const int col = nbase + n0 + j * 16 + (lane & 15);
        const float bv = bias[col];
#pragma unroll
        for (int i = 0; i < 4; ++i) {
#pragma unroll
            for (int r = 0; r < 4; ++r) {
                const size_t rowg = mbase + m0 + i * 16 + (lane >> 4) * 4 + r;
                float v = acc[i][j][r] + bv;
                v = v > 0.f ? v : 0.f;
                C[rowg * 512 + col] = f2h(v);
            }
        }
    }
}

// ---------------- final 512 -> 1 + tanh (fp32 out) ----------------
__global__ __launch_bounds__(256) void out_kernel(const u16* __restrict__ x,
                                                  const float* __restrict__ Wout,
                                                  const float* __restrict__ bout,
                                                  float* __restrict__ out) {
    const int lane = threadIdx.x & 63;
    const int wave = threadIdx.x >> 6;
    const size_t p = (size_t)blockIdx.x * 4 + wave;
    uint4 xv = *(const uint4*)(x + p * 512 + lane * 8);
    const f16* xs = (const f16*)&xv;
    float s = 0.f;
#pragma unroll
    for (int i = 0; i < 8; ++i) s += (float)xs[i] * Wout[lane * 8 + i];
#pragma unroll
    for (int o = 1; o < 64; o <<= 1) s += __shfl_xor(s, o, 64);
    if (lane == 0) out[p] = tanhf(s + bout[0]);
}

extern "C" void kernel_launch(void* const* d_in, const int* in_sizes, int n_in,
                              void* d_out, int out_size, void* d_ws, size_t ws_size,
                              hipStream_t stream) {
    const float* cxyz = (const float*)d_in[0];
    const float* Wf   = (const float*)d_in[1];
    const float* bf   = (const float*)d_in[2];
    const float* Win  = (const float*)d_in[3];
    const float* bin  = (const float*)d_in[4];
    const float* Wh   = (const float*)d_in[5];
    const float* bh   = (const float*)d_in[6];
    const float* Wout = (const float*)d_in[7];
    const float* bout = (const float*)d_in[8];
    float* out = (float*)d_out;
    u16* wsb = (u16*)d_ws;

    const size_t N = NPTS;
    // ws layout (u16 elems), ~352 MB total (ws observed ~1.6 GB)
    u16* xpad = wsb;                                  // N*1568
    u16* xa   = xpad + N * 1568;                      // N*512
    u16* xb   = xa + N * 512;                         // N*512
    u16* W1p  = xb + N * 512;                         // 512*1568
    u16* Winp = W1p + (size_t)512 * 1568;             // 3*512*2080
    u16* Whp  = Winp + (size_t)3 * 512 * 2080;        // 8*512*512

    // 1. KNN + full x_ assembly (f16)
    knn_kernel<<<dim3(N / 4), dim3(256), 0, stream>>>(cxyz, xpad);

    // 2. weight packing
    prep_w1<<<dim3((512 * 1568 + 255) / 256), dim3(256), 0, stream>>>(Wf, W1p);
    prep_win<<<dim3((3 * 512 * 2080 + 255) / 256), dim3(256), 0, stream>>>(Win, Winp);
    prep_wh<<<dim3((8 * 512 * 512 + 255) / 256), dim3(256), 0, stream>>>(Wh, Whp);

    const int MB8 = (int)(N / 128) / 8;               // 64
    const dim3 gg((N / 128) * 4), gb(256);
    const size_t WH = (size_t)512 * 512;
    const size_t WI = (size_t)512 * 2080;

    // 3. MLP (ping-pong xa/xb)
    gemm_f16<<<gg, gb, 0, stream>>>(xpad, 1568, 49, nullptr, 0, 0, W1p, bf, xa, MB8);
    gemm_f16<<<gg, gb, 0, stream>>>(xa, 512, 16, nullptr, 0, 0, Whp + 0 * WH, bh + 0 * 512, xb, MB8);
    gemm_f16<<<gg, gb, 0, stream>>>(xb, 512, 16, nullptr, 0, 0, Whp + 1 * WH, bh + 1 * 512, xa, MB8);

    gemm_f16<<<gg, gb, 0, stream>>>(xa, 512, 16, xpad, 1568, 49, Winp + 0 * WI, bin + 0 * 512, xb, MB8);
    gemm_f16<<<gg, gb, 0, stream>>>(xb, 512, 16, nullptr, 0, 0, Whp + 2 * WH, bh + 2 * 512, xa, MB8);
    gemm_f16<<<gg, gb, 0, stream>>>(xa, 512, 16, nullptr, 0, 0, Whp + 3 * WH, bh + 3 * 512, xb, MB8);

    gemm_f16<<<gg, gb, 0, stream>>>(xb, 512, 16, xpad, 1568, 49, Winp + 1 * WI, bin + 1 * 512, xa, MB8);
    gemm_f16<<<gg, gb, 0, stream>>>(xa, 512, 16, nullptr, 0, 0, Whp + 4 * WH, bh + 4 * 512, xb, MB8);
    gemm_f16<<<gg, gb, 0, stream>>>(xb, 512, 16, nullptr, 0, 0, Whp + 5 * WH, bh + 5 * 512, xa, MB8);

    gemm_f16<<<gg, gb, 0, stream>>>(xa, 512, 16, xpad, 1568, 49, Winp + 2 * WI, bin + 2 * 512, xb, MB8);
    gemm_f16<<<gg, gb, 0, stream>>>(xb, 512, 16, nullptr, 0, 0, Whp + 6 * WH, bh + 6 * 512, xa, MB8);
    gemm_f16<<<gg, gb, 0, stream>>>(xa, 512, 16, nullptr, 0, 0, Whp + 7 * WH, bh + 7 * 512, xb, MB8);

    // 4. output head
    out_kernel<<<dim3(N / 4), dim3(256), 0, stream>>>(xb, Wout, bout, out);
}

// Round 4
// 1806.274 us; speedup vs baseline: 1.0449x; 1.0449x over previous
//
#include <hip/hip_runtime.h>

typedef unsigned short u16;
typedef _Float16 f16;
typedef __attribute__((ext_vector_type(8))) _Float16 f16x8;
typedef __attribute__((ext_vector_type(4))) float f32x4;

#define NPTS 65536

__device__ __forceinline__ u16 f2h(float f) {
    f16 h = (f16)f;  // v_cvt_f16_f32, RNE
    return __builtin_bit_cast(u16, h);
}

__device__ __forceinline__ unsigned pack2(float a, float b) {
    return (unsigned)f2h(a) | ((unsigned)f2h(b) << 16);
}

__device__ __forceinline__ void async_copy16(const u16* g, u16* l) {
    __builtin_amdgcn_global_load_lds(
        (const __attribute__((address_space(1))) void*)g,
        (__attribute__((address_space(3))) void*)l, 16, 0, 0);
}

// ---------------- KNN + full x_ assembly (f16, stride 1568) ----------------
// xpad row: [xyz(3) | sel(24) | zeros(5) | latent(1536)]   (one wave per point)
__global__ __launch_bounds__(256) void knn_kernel(const float* __restrict__ cxyz,
                                                  u16* __restrict__ xpad) {
#pragma clang fp contract(off)
    const int lane = threadIdx.x & 63;
    const int wave = threadIdx.x >> 6;
    const size_t p = (size_t)blockIdx.x * 4 + wave;
    const float* row = cxyz + p * 1539;
    u16* orow = xpad + p * 1568;

    float vals[24];
    const float* lp = row + 3 + lane * 24;
#pragma unroll
    for (int i = 0; i < 24; ++i) vals[i] = lp[i];

    float x0 = row[0], y0 = row[1], z0 = row[2];

    unsigned long long cand[8];
#pragma unroll
    for (int t = 0; t < 8; ++t) {
        float dx = x0 - vals[3 * t + 0];
        float dy = y0 - vals[3 * t + 1];
        float dz = z0 - vals[3 * t + 2];
        float d2 = dx * dx + dy * dy;   // contract off: matches np eval order
        d2 = d2 + dz * dz;
        cand[t] = (((unsigned long long)__float_as_uint(d2)) << 32) |
                  (unsigned)(lane * 8 + t);
    }

    for (int r = 0; r < 8; ++r) {
        unsigned long long m = cand[0];
#pragma unroll
        for (int t = 1; t < 8; ++t) m = (cand[t] < m) ? cand[t] : m;
#pragma unroll
        for (int o = 1; o < 64; o <<= 1) {
            unsigned long long o2 = __shfl_xor(m, o, 64);
            m = (o2 < m) ? o2 : m;
        }
#pragma unroll
        for (int t = 0; t < 8; ++t)
            if (cand[t] == m) cand[t] = ~0ULL;
        if (lane == r) {
            unsigned jw = (unsigned)m;
            orow[3 + 3 * r + 0] = f2h(row[3 + 3 * jw + 0]);
            orow[3 + 3 * r + 1] = f2h(row[3 + 3 * jw + 1]);
            orow[3 + 3 * r + 2] = f2h(row[3 + 3 * jw + 2]);
        }
    }

    if (lane < 3) orow[lane] = f2h(row[lane]);
    if (lane >= 27 && lane < 32) orow[lane] = 0;

    // latent: 24 f16 per lane, 16B-aligned vector stores (64 + 48*lane bytes)
    unsigned w[12];
#pragma unroll
    for (int i = 0; i < 12; ++i) w[i] = pack2(vals[2 * i], vals[2 * i + 1]);
    uint4* op = (uint4*)(orow + 32 + lane * 24);
    op[0] = make_uint4(w[0], w[1], w[2], w[3]);
    op[1] = make_uint4(w[4], w[5], w[6], w[7]);
    op[2] = make_uint4(w[8], w[9], w[10], w[11]);
}

// ---------------- weight packing (fp32 -> f16, transpose + K-pad) ----------------
__global__ __launch_bounds__(256) void prep_w1(const float* __restrict__ Wf,
                                               u16* __restrict__ W1p) {
    int idx = blockIdx.x * 256 + threadIdx.x;
    if (idx >= 512 * 1568) return;
    int n = idx / 1568, kp = idx % 1568;
    float v = 0.f;
    if (kp < 27) v = Wf[(size_t)kp * 512 + n];
    else if (kp >= 32) v = Wf[(size_t)(kp - 5) * 512 + n];
    W1p[idx] = f2h(v);
}

__global__ __launch_bounds__(256) void prep_win(const float* __restrict__ Win,
                                                u16* __restrict__ Winp) {
    int idx = blockIdx.x * 256 + threadIdx.x;
    if (idx >= 3 * 512 * 2080) return;
    int b = idx / (512 * 2080);
    int r = idx % (512 * 2080);
    int n = r / 2080, kp = r % 2080;
    float v = 0.f;
    if (kp < 539) v = Win[((size_t)b * 2075 + kp) * 512 + n];
    else if (kp >= 544) v = Win[((size_t)b * 2075 + kp - 5) * 512 + n];
    Winp[idx] = f2h(v);
}

__global__ __launch_bounds__(256) void prep_wh(const float* __restrict__ Wh,
                                               u16* __restrict__ Whp) {
    int idx = blockIdx.x * 256 + threadIdx.x;
    if (idx >= 8 * 512 * 512) return;
    int m = idx / (512 * 512);
    int r = idx % (512 * 512);
    int n = r / 512, k = r % 512;
    Whp[idx] = f2h(Wh[((size_t)m * 512 + k) * 512 + n]);
}

// ---------------- f16 GEMM: C[M x 512] = relu(A @ B^T + bias) ----------------
// Virtual A = [seg0 (kt0 tiles, ld0) | seg1 (kt1 tiles, ld1)], both f16 k-contiguous.
// B packed transposed [512][K] f16, K = (kt0+kt1)*32. bias fp32. C f16.
//
// v4b = v4 + sched_barrier(0) after s_barrier (raw s_barrier is NOT a compiler
// memory fence; without the fence hipcc may hoist ds_reads above the barrier
// join -> cross-wave race. v3 had this fence and was correct).
//
// Mixed-depth pipeline, 4 blocks/CU preserved (LDS = 40 KB):
//   As[3] (A = activations, L2-cold -> 2-step latency window)
//   Bs[2] (B = weights, L2-hot after first panels -> 1-step window)
// Per step t: wait vmcnt(2)  [queue oldest->new: A(t)x2, B(t)x2, A(t+1)x2
//   -> drains A(t),B(t); A(t+1) stays in flight ACROSS the barrier],
// s_barrier + sched fence, then issue B(t+1), A(t+2). Write-after-read:
// buffer t%3 (resp. t%2) was last read one barrier earlier. Prologue issues
// [B(0),A(0),A(1)] giving the same queue shape.
// XOR swizzle (both-sides, HW-verified in v3): physical quad = logical
// quad ^ row[2:1], applied to the per-lane GLOBAL source column (LDS dest
// stays linear per global_load_lds) and to the ds_read column.
// No setprio / no per-instruction order pinning.
__global__ __launch_bounds__(256, 4) void gemm_f16(
    const u16* __restrict__ A0, int ld0, int kt0,
    const u16* __restrict__ A1, int ld1, int kt1,
    const u16* __restrict__ B,
    const float* __restrict__ bias,
    u16* __restrict__ C,
    int mb8) {                       // (M/128)/8
    __shared__ u16 As[3][128 * 32];
    __shared__ u16 Bs[2][128 * 32];
    const int tid = threadIdx.x;
    const int lane = tid & 63;
    const int wave = tid >> 6;
    const int ktot = kt0 + kt1;
    const size_t ldB = (size_t)ktot * 32;

    // XCD-aware decode: xcd = bid&7 owns M-blocks [xcd*mb8, (xcd+1)*mb8);
    // within the XCD's stream, n cycles fastest -> same-A blocks co-resident.
    const int bid = blockIdx.x;
    const int idx = bid >> 3;
    const int mb = (bid & 7) * mb8 + (idx >> 2);
    const int nb = idx & 3;
    const size_t mbase = (size_t)mb * 128;
    const int nbase = nb * 128;

    f32x4 acc[4][4];
#pragma unroll
    for (int i = 0; i < 4; ++i)
#pragma unroll
        for (int j = 0; j < 4; ++j) acc[i][j] = (f32x4){0.f, 0.f, 0.f, 0.f};

    const int r4 = lane >> 2;         // 0..15 (row within 16-row half)
    // swizzled source column: physical quad q holds logical quad q^row[2:1],
    // so this lane (physical quad lane&3, staged row lane>>2) loads global
    // quad (lane&3)^((lane>>3)&3).
    const int c8s = (((lane & 3) ^ ((lane >> 3) & 3)) * 8);
    const size_t arow0 = mbase + wave * 32 + r4;
    const size_t brow0 = (size_t)nbase + wave * 32 + r4;

    const int m0 = (wave & 1) * 64;
    const int n0 = (wave >> 1) * 64;
    const int rowsel = lane & 15;
    // swizzled read column: physical quad = (lane>>4) ^ rowsel[2:1]
    const int colrd = (((lane >> 4) ^ ((rowsel >> 1) & 3)) * 8);

    auto stageA = [&](int t) {
        u16* l0 = &As[t % 3][(wave * 32 + 0) * 32];
        u16* l1 = &As[t % 3][(wave * 32 + 16) * 32];
        if (t < kt0) {
            const size_t off = arow0 * (size_t)ld0 + t * 32 + c8s;
            async_copy16(A0 + off, l0);
            async_copy16(A0 + off + 16 * (size_t)ld0, l1);
        } else {
            const size_t off = arow0 * (size_t)ld1 + (t - kt0) * 32 + c8s;
            async_copy16(A1 + off, l0);
            async_copy16(A1 + off + 16 * (size_t)ld1, l1);
        }
    };
    auto stageB = [&](int t) {
        u16* l0 = &Bs[t & 1][(wave * 32 + 0) * 32];
        u16* l1 = &Bs[t & 1][(wave * 32 + 16) * 32];
        const size_t boff = brow0 * ldB + t * 32 + c8s;
        async_copy16(B + boff, l0);
        async_copy16(B + boff + 16 * ldB, l1);
    };

    // prologue: queue = [B(0)x2, A(0)x2, A(1)x2]
    stageB(0);
    stageA(0);
    if (1 < ktot) stageA(1);

    for (int t = 0; t < ktot; ++t) {
        const int ca = t % 3;
        const int cb = t & 1;
        // drain A(t)+B(t); keep A(t+1) in flight across the barrier
        if (t + 1 < ktot) {
            asm volatile("s_waitcnt vmcnt(2)" ::: "memory");
        } else {
            asm volatile("s_waitcnt vmcnt(0)" ::: "memory");
        }
        __builtin_amdgcn_s_barrier();
        __builtin_amdgcn_sched_barrier(0);  // pin ds_reads below the barrier
        // issue next loads into buffers freed at an earlier barrier
        if (t + 1 < ktot) stageB(t + 1);
        if (t + 2 < ktot) stageA(t + 2);

        f16x8 af[4], bfr[4];
#pragma unroll
        for (int i = 0; i < 4; ++i) {
            af[i]  = __builtin_bit_cast(f16x8, *(const uint4*)&As[ca][(m0 + i * 16 + rowsel) * 32 + colrd]);
            bfr[i] = __builtin_bit_cast(f16x8, *(const uint4*)&Bs[cb][(n0 + i * 16 + rowsel) * 32 + colrd]);
        }
#pragma unroll
        for (int i = 0; i < 4; ++i)
#pragma unroll
            for (int j = 0; j < 4; ++j)
                acc[i][j] = __builtin_amdgcn_mfma_f32_16x16x32_f16(
                    af[i], bfr[j], acc[i][j], 0, 0, 0);
    }

    // epilogue: bias + relu -> f16. D layout: col=lane&15, row=(lane>>4)*4+reg
#pragma unroll
    for (int j = 0; j < 4; ++j) {
        const int col = nbase + n0 + j * 16 + (lane & 15);
        const float bv = bias[col];
#pragma unroll
        for (int i = 0; i < 4; ++i) {
#pragma unroll
            for (int r = 0; r < 4; ++r) {
                const size_t rowg = mbase + m0 + i * 16 + (lane >> 4) * 4 + r;
                float v = acc[i][j][r] + bv;
                v = v > 0.f ? v : 0.f;
                C[rowg * 512 + col] = f2h(v);
            }
        }
    }
}

// ---------------- final 512 -> 1 + tanh (fp32 out) ----------------
__global__ __launch_bounds__(256) void out_kernel(const u16* __restrict__ x,
                                                  const float* __restrict__ Wout,
                                                  const float* __restrict__ bout,
                                                  float* __restrict__ out) {
    const int lane = threadIdx.x & 63;
    const int wave = threadIdx.x >> 6;
    const size_t p = (size_t)blockIdx.x * 4 + wave;
    uint4 xv = *(const uint4*)(x + p * 512 + lane * 8);
    const f16* xs = (const f16*)&xv;
    float s = 0.f;
#pragma unroll
    for (int i = 0; i < 8; ++i) s += (float)xs[i] * Wout[lane * 8 + i];
#pragma unroll
    for (int o = 1; o < 64; o <<= 1) s += __shfl_xor(s, o, 64);
    if (lane == 0) out[p] = tanhf(s + bout[0]);
}

extern "C" void kernel_launch(void* const* d_in, const int* in_sizes, int n_in,
                              void* d_out, int out_size, void* d_ws, size_t ws_size,
                              hipStream_t stream) {
    const float* cxyz = (const float*)d_in[0];
    const float* Wf   = (const float*)d_in[1];
    const float* bf   = (const float*)d_in[2];
    const float* Win  = (const float*)d_in[3];
    const float* bin  = (const float*)d_in[4];
    const float* Wh   = (const float*)d_in[5];
    const float* bh   = (const float*)d_in[6];
    const float* Wout = (const float*)d_in[7];
    const float* bout = (const float*)d_in[8];
    float* out = (float*)d_out;
    u16* wsb = (u16*)d_ws;

    const size_t N = NPTS;
    // ws layout (u16 elems), ~352 MB total (ws observed ~1.6 GB)
    u16* xpad = wsb;                                  // N*1568
    u16* xa   = xpad + N * 1568;                      // N*512
    u16* xb   = xa + N * 512;                         // N*512
    u16* W1p  = xb + N * 512;                         // 512*1568
    u16* Winp = W1p + (size_t)512 * 1568;             // 3*512*2080
    u16* Whp  = Winp + (size_t)3 * 512 * 2080;        // 8*512*512

    // 1. KNN + full x_ assembly (f16)
    knn_kernel<<<dim3(N / 4), dim3(256), 0, stream>>>(cxyz, xpad);

    // 2. weight packing
    prep_w1<<<dim3((512 * 1568 + 255) / 256), dim3(256), 0, stream>>>(Wf, W1p);
    prep_win<<<dim3((3 * 512 * 2080 + 255) / 256), dim3(256), 0, stream>>>(Win, Winp);
    prep_wh<<<dim3((8 * 512 * 512 + 255) / 256), dim3(256), 0, stream>>>(Wh, Whp);

    const int MB8 = (int)(N / 128) / 8;               // 64
    const dim3 gg((N / 128) * 4), gb(256);
    const size_t WH = (size_t)512 * 512;
    const size_t WI = (size_t)512 * 2080;

    // 3. MLP (ping-pong xa/xb)
    gemm_f16<<<gg, gb, 0, stream>>>(xpad, 1568, 49, nullptr, 0, 0, W1p, bf, xa, MB8);
    gemm_f16<<<gg, gb, 0, stream>>>(xa, 512, 16, nullptr, 0, 0, Whp + 0 * WH, bh + 0 * 512, xb, MB8);
    gemm_f16<<<gg, gb, 0, stream>>>(xb, 512, 16, nullptr, 0, 0, Whp + 1 * WH, bh + 1 * 512, xa, MB8);

    gemm_f16<<<gg, gb, 0, stream>>>(xa, 512, 16, xpad, 1568, 49, Winp + 0 * WI, bin + 0 * 512, xb, MB8);
    gemm_f16<<<gg, gb, 0, stream>>>(xb, 512, 16, nullptr, 0, 0, Whp + 2 * WH, bh + 2 * 512, xa, MB8);
    gemm_f16<<<gg, gb, 0, stream>>>(xa, 512, 16, nullptr, 0, 0, Whp + 3 * WH, bh + 3 * 512, xb, MB8);

    gemm_f16<<<gg, gb, 0, stream>>>(xb, 512, 16, xpad, 1568, 49, Winp + 1 * WI, bin + 1 * 512, xa, MB8);
    gemm_f16<<<gg, gb, 0, stream>>>(xa, 512, 16, nullptr, 0, 0, Whp + 4 * WH, bh + 4 * 512, xb, MB8);
    gemm_f16<<<gg, gb, 0, stream>>>(xb, 512, 16, nullptr, 0, 0, Whp + 5 * WH, bh + 5 * 512, xa, MB8);

    gemm_f16<<<gg, gb, 0, stream>>>(xa, 512, 16, xpad, 1568, 49, Winp + 2 * WI, bin + 2 * 512, xb, MB8);
    gemm_f16<<<gg, gb, 0, stream>>>(xb, 512, 16, nullptr, 0, 0, Whp + 6 * WH, bh + 6 * 512, xa, MB8);
    gemm_f16<<<gg, gb, 0, stream>>>(xa, 512, 16, nullptr, 0, 0, Whp + 7 * WH, bh + 7 * 512, xb, MB8);

    // 4. output head
    out_kernel<<<dim3(N / 4), dim3(256), 0, stream>>>(xb, Wout, bout, out);
}

// Round 5
// 1755.099 us; speedup vs baseline: 1.0753x; 1.0292x over previous
//
#include <hip/hip_runtime.h>

typedef unsigned short u16;
typedef _Float16 f16;
typedef __attribute__((ext_vector_type(8))) _Float16 f16x8;
typedef __attribute__((ext_vector_type(4))) float f32x4;

#define NPTS 65536

__device__ __forceinline__ u16 f2h(float f) {
    f16 h = (f16)f;  // v_cvt_f16_f32, RNE
    return __builtin_bit_cast(u16, h);
}

__device__ __forceinline__ unsigned pack2(float a, float b) {
    return (unsigned)f2h(a) | ((unsigned)f2h(b) << 16);
}

__device__ __forceinline__ void async_copy16(const u16* g, u16* l) {
    __builtin_amdgcn_global_load_lds(
        (const __attribute__((address_space(1))) void*)g,
        (__attribute__((address_space(3))) void*)l, 16, 0, 0);
}

// ---------------- KNN + full x_ assembly (f16, stride 1568) ----------------
// xpad row: [xyz(3) | sel(24) | zeros(5) | latent(1536)]   (one wave per point)
__global__ __launch_bounds__(256) void knn_kernel(const float* __restrict__ cxyz,
                                                  u16* __restrict__ xpad) {
#pragma clang fp contract(off)
    const int lane = threadIdx.x & 63;
    const int wave = threadIdx.x >> 6;
    const size_t p = (size_t)blockIdx.x * 4 + wave;
    const float* row = cxyz + p * 1539;
    u16* orow = xpad + p * 1568;

    float vals[24];
    const float* lp = row + 3 + lane * 24;
#pragma unroll
    for (int i = 0; i < 24; ++i) vals[i] = lp[i];

    float x0 = row[0], y0 = row[1], z0 = row[2];

    unsigned long long cand[8];
#pragma unroll
    for (int t = 0; t < 8; ++t) {
        float dx = x0 - vals[3 * t + 0];
        float dy = y0 - vals[3 * t + 1];
        float dz = z0 - vals[3 * t + 2];
        float d2 = dx * dx + dy * dy;   // contract off: matches np eval order
        d2 = d2 + dz * dz;
        cand[t] = (((unsigned long long)__float_as_uint(d2)) << 32) |
                  (unsigned)(lane * 8 + t);
    }

    for (int r = 0; r < 8; ++r) {
        unsigned long long m = cand[0];
#pragma unroll
        for (int t = 1; t < 8; ++t) m = (cand[t] < m) ? cand[t] : m;
#pragma unroll
        for (int o = 1; o < 64; o <<= 1) {
            unsigned long long o2 = __shfl_xor(m, o, 64);
            m = (o2 < m) ? o2 : m;
        }
#pragma unroll
        for (int t = 0; t < 8; ++t)
            if (cand[t] == m) cand[t] = ~0ULL;
        if (lane == r) {
            unsigned jw = (unsigned)m;
            orow[3 + 3 * r + 0] = f2h(row[3 + 3 * jw + 0]);
            orow[3 + 3 * r + 1] = f2h(row[3 + 3 * jw + 1]);
            orow[3 + 3 * r + 2] = f2h(row[3 + 3 * jw + 2]);
        }
    }

    if (lane < 3) orow[lane] = f2h(row[lane]);
    if (lane >= 27 && lane < 32) orow[lane] = 0;

    // latent: 24 f16 per lane, 16B-aligned vector stores (64 + 48*lane bytes)
    unsigned w[12];
#pragma unroll
    for (int i = 0; i < 12; ++i) w[i] = pack2(vals[2 * i], vals[2 * i + 1]);
    uint4* op = (uint4*)(orow + 32 + lane * 24);
    op[0] = make_uint4(w[0], w[1], w[2], w[3]);
    op[1] = make_uint4(w[4], w[5], w[6], w[7]);
    op[2] = make_uint4(w[8], w[9], w[10], w[11]);
}

// ---------------- weight packing (fp32 -> f16, transpose + K-pad) ----------------
__global__ __launch_bounds__(256) void prep_w1(const float* __restrict__ Wf,
                                               u16* __restrict__ W1p) {
    int idx = blockIdx.x * 256 + threadIdx.x;
    if (idx >= 512 * 1568) return;
    int n = idx / 1568, kp = idx % 1568;
    float v = 0.f;
    if (kp < 27) v = Wf[(size_t)kp * 512 + n];
    else if (kp >= 32) v = Wf[(size_t)(kp - 5) * 512 + n];
    W1p[idx] = f2h(v);
}

__global__ __launch_bounds__(256) void prep_win(const float* __restrict__ Win,
                                                u16* __restrict__ Winp) {
    int idx = blockIdx.x * 256 + threadIdx.x;
    if (idx >= 3 * 512 * 2080) return;
    int b = idx / (512 * 2080);
    int r = idx % (512 * 2080);
    int n = r / 2080, kp = r % 2080;
    float v = 0.f;
    if (kp < 539) v = Win[((size_t)b * 2075 + kp) * 512 + n];
    else if (kp >= 544) v = Win[((size_t)b * 2075 + kp - 5) * 512 + n];
    Winp[idx] = f2h(v);
}

__global__ __launch_bounds__(256) void prep_wh(const float* __restrict__ Wh,
                                               u16* __restrict__ Whp) {
    int idx = blockIdx.x * 256 + threadIdx.x;
    if (idx >= 8 * 512 * 512) return;
    int m = idx / (512 * 512);
    int r = idx % (512 * 512);
    int n = r / 512, k = r % 512;
    Whp[idx] = f2h(Wh[((size_t)m * 512 + k) * 512 + n]);
}

// ---------------- f16 GEMM: C[M x 512] = relu(A @ B^T + bias) ----------------
// Virtual A = [seg0 (kt0 tiles, ld0) | seg1 (kt1 tiles, ld1)], both f16 k-contiguous.
// B packed transposed [512][K] f16, K = (kt0+kt1)*32. bias fp32. C f16.
//
// v5 = v2 champion structure (UNCHANGED: 2-buf prefetch-before-compute,
// __syncthreads per step, 32 KB LDS -> 5 blocks/CU, XCD-chunked remap)
// + the XOR bank swizzle as the single variable.
//   Mechanism: [row][32] u16 rows have 64 B pitch, so the 16-lane groups of
//   a ds_read_b128 hit banks {0-3,16-19} only (8-way serialize; measured
//   1.7e7 conflict cycles ~ 9.5% of GEMM time in round 0). Swizzle:
//   physical quad = logical quad ^ row[2:1] -> rows 0-7 cover all 32 banks
//   once; residual 2-way is free (m136). Both-sides application (rule #21):
//   LDS dest stays LINEAR (global_load_lds requirement); the involution is
//   applied to the per-lane GLOBAL source column and to the ds_read column.
//   Ran bit-correct inside v3/v4b.
// Occupancy lesson (v3/v4b post-mortem): blocks/CU {5,4,3} -> {1768,1806,
// 1887} us. Deeper counted-vmcnt pipelines lose more TLP than they gain;
// do NOT trade LDS for pipeline depth at this tile size.
__global__ __launch_bounds__(256, 4) void gemm_f16(
    const u16* __restrict__ A0, int ld0, int kt0,
    const u16* __restrict__ A1, int ld1, int kt1,
    const u16* __restrict__ B,
    const float* __restrict__ bias,
    u16* __restrict__ C,
    int mb8) {                       // (M/128)/8
    __shared__ u16 As[2][128 * 32];
    __shared__ u16 Bs[2][128 * 32];
    const int tid = threadIdx.x;
    const int lane = tid & 63;
    const int wave = tid >> 6;
    const int ktot = kt0 + kt1;
    const size_t ldB = (size_t)ktot * 32;

    // XCD-aware decode: xcd = bid&7 owns M-blocks [xcd*mb8, (xcd+1)*mb8);
    // within the XCD's stream, n cycles fastest -> same-A blocks co-resident.
    const int bid = blockIdx.x;
    const int idx = bid >> 3;
    const int mb = (bid & 7) * mb8 + (idx >> 2);
    const int nb = idx & 3;
    const size_t mbase = (size_t)mb * 128;
    const int nbase = nb * 128;

    f32x4 acc[4][4];
#pragma unroll
    for (int i = 0; i < 4; ++i)
#pragma unroll
        for (int j = 0; j < 4; ++j) acc[i][j] = (f32x4){0.f, 0.f, 0.f, 0.f};

    const int r4 = lane >> 2;         // 0..15 (staged row within 16-row half)
    // swizzled source column: physical quad (lane&3) of staged row (lane>>2)
    // holds logical quad (lane&3)^row[2:1]; row[2:1] = (lane>>3)&3.
    // (rows 16-31 add 16 -> bit4 only, bits[2:1] unchanged.)
    const int c8s = (((lane & 3) ^ ((lane >> 3) & 3)) * 8);
    const size_t arow0 = mbase + wave * 32 + r4;
    const size_t brow0 = (size_t)nbase + wave * 32 + r4;

    const int m0 = (wave & 1) * 64;
    const int n0 = (wave >> 1) * 64;
    const int rowsel = lane & 15;
    // swizzled read column: logical quad (lane>>4) of row ..+rowsel lives at
    // physical quad (lane>>4) ^ rowsel[2:1] (m0/n0/i*16 only touch bits>=4).
    const int colrd = (((lane >> 4) ^ ((rowsel >> 1) & 3)) * 8);

    auto stage = [&](int t, int b) {
        u16* lA0 = &As[b][(wave * 32 + 0) * 32];
        u16* lA1 = &As[b][(wave * 32 + 16) * 32];
        u16* lB0 = &Bs[b][(wave * 32 + 0) * 32];
        u16* lB1 = &Bs[b][(wave * 32 + 16) * 32];
        if (t < kt0) {
            const size_t off = arow0 * (size_t)ld0 + t * 32 + c8s;
            async_copy16(A0 + off, lA0);
            async_copy16(A0 + off + 16 * (size_t)ld0, lA1);
        } else {
            const size_t off = arow0 * (size_t)ld1 + (t - kt0) * 32 + c8s;
            async_copy16(A1 + off, lA0);
            async_copy16(A1 + off + 16 * (size_t)ld1, lA1);
        }
        const size_t boff = brow0 * ldB + t * 32 + c8s;
        async_copy16(B + boff, lB0);
        async_copy16(B + boff + 16 * ldB, lB1);
    };

    // prologue: fill buffer 0
    stage(0, 0);
    __syncthreads();

    int cur = 0;
    for (int t = 0; t < ktot; ++t) {
        // issue next tile's loads BEFORE compute -> HBM latency hides under MFMA
        if (t + 1 < ktot) stage(t + 1, cur ^ 1);

        f16x8 af[4], bfr[4];
#pragma unroll
        for (int i = 0; i < 4; ++i) {
            af[i]  = __builtin_bit_cast(f16x8, *(const uint4*)&As[cur][(m0 + i * 16 + rowsel) * 32 + colrd]);
            bfr[i] = __builtin_bit_cast(f16x8, *(const uint4*)&Bs[cur][(n0 + i * 16 + rowsel) * 32 + colrd]);
        }
#pragma unroll
        for (int i = 0; i < 4; ++i)
#pragma unroll
            for (int j = 0; j < 4; ++j)
                acc[i][j] = __builtin_amdgcn_mfma_f32_16x16x32_f16(
                    af[i], bfr[j], acc[i][j], 0, 0, 0);

        // one barrier per step: drains vmcnt(0) (next tile staged) and
        // guarantees all waves done reading buf[cur] before it is rewritten
        __syncthreads();
        cur ^= 1;
    }

    // epilogue: bias + relu -> f16. D layout: col=lane&15, row=(lane>>4)*4+reg
#pragma unroll
    for (int j = 0; j < 4; ++j) {
        const int col = nbase + n0 + j * 16 + (lane & 15);
        const float bv = bias[col];
#pragma unroll
        for (int i = 0; i < 4; ++i) {
#pragma unroll
            for (int r = 0; r < 4; ++r) {
                const size_t rowg = mbase + m0 + i * 16 + (lane >> 4) * 4 + r;
                float v = acc[i][j][r] + bv;
                v = v > 0.f ? v : 0.f;
                C[rowg * 512 + col] = f2h(v);
            }
        }
    }
}

// ---------------- final 512 -> 1 + tanh (fp32 out) ----------------
__global__ __launch_bounds__(256) void out_kernel(const u16* __restrict__ x,
                                                  const float* __restrict__ Wout,
                                                  const float* __restrict__ bout,
                                                  float* __restrict__ out) {
    const int lane = threadIdx.x & 63;
    const int wave = threadIdx.x >> 6;
    const size_t p = (size_t)blockIdx.x * 4 + wave;
    uint4 xv = *(const uint4*)(x + p * 512 + lane * 8);
    const f16* xs = (const f16*)&xv;
    float s = 0.f;
#pragma unroll
    for (int i = 0; i < 8; ++i) s += (float)xs[i] * Wout[lane * 8 + i];
#pragma unroll
    for (int o = 1; o < 64; o <<= 1) s += __shfl_xor(s, o, 64);
    if (lane == 0) out[p] = tanhf(s + bout[0]);
}

extern "C" void kernel_launch(void* const* d_in, const int* in_sizes, int n_in,
                              void* d_out, int out_size, void* d_ws, size_t ws_size,
                              hipStream_t stream) {
    const float* cxyz = (const float*)d_in[0];
    const float* Wf   = (const float*)d_in[1];
    const float* bf   = (const float*)d_in[2];
    const float* Win  = (const float*)d_in[3];
    const float* bin  = (const float*)d_in[4];
    const float* Wh   = (const float*)d_in[5];
    const float* bh   = (const float*)d_in[6];
    const float* Wout = (const float*)d_in[7];
    const float* bout = (const float*)d_in[8];
    float* out = (float*)d_out;
    u16* wsb = (u16*)d_ws;

    const size_t N = NPTS;
    // ws layout (u16 elems), ~352 MB total (ws observed ~1.6 GB)
    u16* xpad = wsb;                                  // N*1568
    u16* xa   = xpad + N * 1568;                      // N*512
    u16* xb   = xa + N * 512;                         // N*512
    u16* W1p  = xb + N * 512;                         // 512*1568
    u16* Winp = W1p + (size_t)512 * 1568;             // 3*512*2080
    u16* Whp  = Winp + (size_t)3 * 512 * 2080;        // 8*512*512

    // 1. KNN + full x_ assembly (f16)
    knn_kernel<<<dim3(N / 4), dim3(256), 0, stream>>>(cxyz, xpad);

    // 2. weight packing
    prep_w1<<<dim3((512 * 1568 + 255) / 256), dim3(256), 0, stream>>>(Wf, W1p);
    prep_win<<<dim3((3 * 512 * 2080 + 255) / 256), dim3(256), 0, stream>>>(Win, Winp);
    prep_wh<<<dim3((8 * 512 * 512 + 255) / 256), dim3(256), 0, stream>>>(Wh, Whp);

    const int MB8 = (int)(N / 128) / 8;               // 64
    const dim3 gg((N / 128) * 4), gb(256);
    const size_t WH = (size_t)512 * 512;
    const size_t WI = (size_t)512 * 2080;

    // 3. MLP (ping-pong xa/xb)
    gemm_f16<<<gg, gb, 0, stream>>>(xpad, 1568, 49, nullptr, 0, 0, W1p, bf, xa, MB8);
    gemm_f16<<<gg, gb, 0, stream>>>(xa, 512, 16, nullptr, 0, 0, Whp + 0 * WH, bh + 0 * 512, xb, MB8);
    gemm_f16<<<gg, gb, 0, stream>>>(xb, 512, 16, nullptr, 0, 0, Whp + 1 * WH, bh + 1 * 512, xa, MB8);

    gemm_f16<<<gg, gb, 0, stream>>>(xa, 512, 16, xpad, 1568, 49, Winp + 0 * WI, bin + 0 * 512, xb, MB8);
    gemm_f16<<<gg, gb, 0, stream>>>(xb, 512, 16, nullptr, 0, 0, Whp + 2 * WH, bh + 2 * 512, xa, MB8);
    gemm_f16<<<gg, gb, 0, stream>>>(xa, 512, 16, nullptr, 0, 0, Whp + 3 * WH, bh + 3 * 512, xb, MB8);

    gemm_f16<<<gg, gb, 0, stream>>>(xb, 512, 16, xpad, 1568, 49, Winp + 1 * WI, bin + 1 * 512, xa, MB8);
    gemm_f16<<<gg, gb, 0, stream>>>(xa, 512, 16, nullptr, 0, 0, Whp + 4 * WH, bh + 4 * 512, xb, MB8);
    gemm_f16<<<gg, gb, 0, stream>>>(xb, 512, 16, nullptr, 0, 0, Whp + 5 * WH, bh + 5 * 512, xa, MB8);

    gemm_f16<<<gg, gb, 0, stream>>>(xa, 512, 16, xpad, 1568, 49, Winp + 2 * WI, bin + 2 * 512, xb, MB8);
    gemm_f16<<<gg, gb, 0, stream>>>(xb, 512, 16, nullptr, 0, 0, Whp + 6 * WH, bh + 6 * 512, xa, MB8);
    gemm_f16<<<gg, gb, 0, stream>>>(xa, 512, 16, nullptr, 0, 0, Whp + 7 * WH, bh + 7 * 512, xb, MB8);

    // 4. output head
    out_kernel<<<dim3(N / 4), dim3(256), 0, stream>>>(xb, Wout, bout, out);
}